// Round 2
// baseline (237.725 us; speedup 1.0000x reference)
//
#include <hip/hip_runtime.h>

// Dynamics compressor: audio_db = 20*log10(|a|+1e-5);
// grd = max((thr-db)*(1-1/ratio), 0);
// g[t] = g[t-1] + (1-coeff)*(grd[t]-g[t-1]), coeff = att if grd>g else rel;
// out = a * 10^(-g/20)
//
// Chunked-parallel via contraction: |dg'/dg| = coeff <= 0.1, so a W=12
// warm-up from g=0 makes per-thread chunks exact to f32 (err <= 60*1e-12).
//
// R5 == R4 resubmit (both prior rounds died to infra before running).
// R4 theory: prior best 239.6 us is ~5.6x over the 268MB/6.3TBps HBM
// floor of ~43 us -> latency/occupancy-bound, not BW-bound. Changes:
//  1. C 32->16 + un-padded XOR-swizzled LDS (16 KiB/block):
//     4 blocks/CU (50% occ) -> 8 blocks/CU (32 waves, 100% occ).
//     Swizzle slot(li) = (li&~31) | ((li&31) ^ ((li>>5)&31)) is bijective
//     per 32-word group; every access pattern here is 2-way on banks (free).
//  2. Warm-up samples read from LDS (= previous thread's chunk tail)
//     instead of 3 uncoalesced global float4/thread (was 64 sector
//     requests/wave/instr, ~2.5x request amplification on the load path).
//     Only tid==0 reads its 12-float history from global (prev tile tail).
//     Extra barrier orders neighbor-tail reads before in-place stage C.
//  3. Recurrence restructured to g' = max(att*g+(1-att)*grd,
//     rel*g+(1-rel)*grd). Exact vs the branch: ga-gr = (rel-att)*(grd-g),
//     rel>att -> max picks attack-form iff grd>g. Dependent chain per step
//     = {fma || fma} -> max (~8 cyc) instead of cmp->cndmask->sub->fma.
//     All log2 (stage A) and exp2 (stage C) hoisted out of the chain so
//     the trans pipe pipelines across independent samples.

constexpr int T = 256;        // threads per block (4 waves)
constexpr int C = 16;         // samples per thread
constexpr int TILE = T * C;   // 4096 samples, 16 KiB LDS
constexpr int W = 12;         // warm-up lookback (contraction 1e-12)

// XOR bank swizzle, bijective within each 32-float group.
__device__ __forceinline__ int sw(int li) {
    return (li & ~31) | ((li & 31) ^ ((li >> 5) & 31));
}

__global__ __launch_bounds__(T) void compressor_kernel(
    const float* __restrict__ audio,
    const float* __restrict__ thr_p,
    const float* __restrict__ ratio_p,
    const float* __restrict__ att_p,
    const float* __restrict__ rel_p,
    float* __restrict__ out)
{
    __shared__ float buf[TILE]; // 16384 B -> 8 blocks/CU (wave-capped)

    const int tid = threadIdx.x;
    const long long tile0 = (long long)blockIdx.x * TILE;

    const float thr   = *thr_p;
    const float ratio = *ratio_p;
    const float att   = *att_p;
    const float rel   = *rel_p;
    const float sfac  = 1.0f - 1.0f / ratio;
    const float GA    = thr * sfac;                     // grd = max(GB2*log2(y)+GA, 0)
    const float GB2   = -20.0f * sfac * 0.30102999566f; // log10(y) = log2(y)*log10(2)
    const float KEXP  = -0.05f * 3.32192809489f;        // 10^(-g/20) = 2^(KEXP*g)
    const float omc_att = 1.0f - att;
    const float omc_rel = 1.0f - rel;

    const bool has_warm = (blockIdx.x > 0) || (tid > 0); // false only at t=0

    // tid==0's 12-sample history lives in the PREVIOUS tile -> global.
    // Issued before phase 1 so its latency hides under the tile load.
    float4 wg0 = {0,0,0,0}, wg1 = {0,0,0,0}, wg2 = {0,0,0,0};
    if (tid == 0 && blockIdx.x > 0) {
        const float4* wp = reinterpret_cast<const float4*>(audio + tile0 - W);
        wg0 = wp[0]; wg1 = wp[1]; wg2 = wp[2]; // 48B, 16B-aligned
    }

    // ---- Phase 1: coalesced float4 global -> swizzled LDS ----
    const float4* a4 = reinterpret_cast<const float4*>(audio + tile0);
#pragma unroll
    for (int k = 0; k < C / 4; ++k) {
        const int idx4 = k * T + tid;
        const float4 v = a4[idx4];
        const int li   = idx4 * 4;
        const int base = li & ~31;
        const int j0   = li & 31;          // 4-aligned
        const int key  = (li >> 5) & 31;
        buf[base + ((j0 + 0) ^ key)] = v.x;
        buf[base + ((j0 + 1) ^ key)] = v.y;
        buf[base + ((j0 + 2) ^ key)] = v.z;
        buf[base + ((j0 + 3) ^ key)] = v.w;
    }
    __syncthreads();

    // ---- Warm-up samples: previous chunk's tail (LDS), tid==0 from global
    float xw[W];
    if (tid > 0) {
        const int p0 = (tid - 1) * C + (C - W); // first warm-up element index
#pragma unroll
        for (int i = 0; i < W; ++i)
            xw[i] = buf[sw(p0 + i)];
    } else {
        xw[0]=wg0.x; xw[1]=wg0.y; xw[2] =wg0.z; xw[3] =wg0.w;
        xw[4]=wg1.x; xw[5]=wg1.y; xw[6] =wg1.z; xw[7] =wg1.w;
        xw[8]=wg2.x; xw[9]=wg2.y; xw[10]=wg2.z; xw[11]=wg2.w;
    }
    // Order neighbor-tail reads before anyone's in-place stage-C writes.
    __syncthreads();

    // ---- Stage A: all grd values (independent -> trans ops pipeline) ----
    float grdw[W], grdm[C];
#pragma unroll
    for (int i = 0; i < W; ++i) {
        const float y = fabsf(xw[i]) + 1e-5f;
        grdw[i] = fmaxf(fmaf(GB2, __log2f(y), GA), 0.0f);
    }
    const int myb = tid * C;
#pragma unroll
    for (int j = 0; j < C; ++j) {
        const float y = fabsf(buf[sw(myb + j)]) + 1e-5f;
        grdm[j] = fmaxf(fmaf(GB2, __log2f(y), GA), 0.0f);
    }

    // ---- Stage B: tight recurrence, chain = {fma || fma} -> max ----
    float g = 0.0f;
    if (has_warm) {
#pragma unroll
        for (int i = 0; i < W; ++i) {
            const float ga = fmaf(att, g, omc_att * grdw[i]);
            const float gr = fmaf(rel, g, omc_rel * grdw[i]);
            g = fmaxf(ga, gr);
        }
    }
#pragma unroll
    for (int j = 0; j < C; ++j) {
        const float ga = fmaf(att, g, omc_att * grdm[j]);
        const float gr = fmaf(rel, g, omc_rel * grdm[j]);
        g = fmaxf(ga, gr);
        grdm[j] = g; // reuse register array for the smoothed gain
    }

    // ---- Stage C: out = x * 2^(KEXP*g), in place in LDS ----
#pragma unroll
    for (int j = 0; j < C; ++j) {
        const int s = sw(myb + j);
        buf[s] = buf[s] * __builtin_amdgcn_exp2f(KEXP * grdm[j]);
    }
    __syncthreads();

    // ---- Phase 3: swizzled LDS -> coalesced float4 global ----
    float4* o4 = reinterpret_cast<float4*>(out + tile0);
#pragma unroll
    for (int k = 0; k < C / 4; ++k) {
        const int idx4 = k * T + tid;
        const int li   = idx4 * 4;
        const int base = li & ~31;
        const int j0   = li & 31;
        const int key  = (li >> 5) & 31;
        float4 v;
        v.x = buf[base + ((j0 + 0) ^ key)];
        v.y = buf[base + ((j0 + 1) ^ key)];
        v.z = buf[base + ((j0 + 2) ^ key)];
        v.w = buf[base + ((j0 + 3) ^ key)];
        o4[idx4] = v;
    }
}

extern "C" void kernel_launch(void* const* d_in, const int* in_sizes, int n_in,
                              void* d_out, int out_size, void* d_ws, size_t ws_size,
                              hipStream_t stream) {
    const float* audio = (const float*)d_in[0];
    // d_in[1] = sample_rate (int) — unused by the reference math
    const float* thr   = (const float*)d_in[2];
    const float* ratio = (const float*)d_in[3];
    const float* att   = (const float*)d_in[4];
    const float* rel   = (const float*)d_in[5];
    float* outp = (float*)d_out;

    const int n = in_sizes[0];   // 1<<25 elements, divisible by TILE (4096)
    const int grid = n / TILE;   // 8192 blocks
    compressor_kernel<<<grid, T, 0, stream>>>(audio, thr, ratio, att, rel, outp);
}

// Round 6
// 235.373 us; speedup vs baseline: 1.0100x; 1.0100x over previous
//
#include <hip/hip_runtime.h>

// Dynamics compressor: audio_db = 20*log10(|a|+1e-5);
// grd = max((thr-db)*(1-1/ratio), 0);
// g[t] = g[t-1] + (1-coeff)*(grd[t]-g[t-1]), coeff = att if grd>g else rel;
// out = a * 10^(-g/20)
//
// Chunked-parallel via contraction: |dg'/dg| = coeff <= 0.1, so a W=12
// warm-up from g=0 makes per-thread chunks exact to f32 (err <= 60*1e-12).
//
// R9 == R6 resubmit (R6/R7/R8 all died to GPU-acquisition timeouts — the
// broker fails before the kernel is compiled/pushed, so content is moot).
// R6: barrier-free wave-local restructure.
// R5 measured: kernel dispatch 79.7 us vs 40 us HBM floor (256 MB @ 6.3),
// occupancy 55%, VALUBusy 32%, bank-conflicts negligible. Harness dur_us
// (237.7) = 2x80us harness fills + kernel; only the kernel is ours.
// Theory: the 3 __syncthreads() serialize {mem, compute} phases per block,
// dropping in-flight bytes below the Little's-law requirement (~9 KB/CU).
// Fix: each WAVE owns a 1024-sample region; phase-1 loads are re-mapped so
// all LDS producer->consumer pairs are same-wave (lane l's warm-up tail =
// lane l-1's chunk tail; wave lockstep + in-order DS pipe make this safe
// with only an lgkmcnt fence, no barrier). Lane 0 of each wave (4/block)
// reads its 12-sample history from global. ZERO barriers -> waves free-run,
// memory phases of different waves overlap compute phases of others.

constexpr int T = 256;        // threads per block (4 independent waves)
constexpr int C = 16;         // samples per thread
constexpr int WREG = 64 * C;  // 1024 samples per wave region
constexpr int TILE = T * C;   // 4096 samples per block, 16 KiB LDS
constexpr int W = 12;         // warm-up lookback (contraction 1e-12)

// XOR bank swizzle, bijective within each 32-float group.
// Stage A/C pattern (lane l, word (l&1)*16+j, key (l>>1)&31) -> exactly
// 2 lanes/bank = free. Phase 1/3 b128 pattern unchanged from R5 (measured
// conflicts 688K cyc ~ 1.4%, negligible).
__device__ __forceinline__ int sw(int li) {
    return (li & ~31) | ((li & 31) ^ ((li >> 5) & 31));
}

__global__ __launch_bounds__(T) void compressor_kernel(
    const float* __restrict__ audio,
    const float* __restrict__ thr_p,
    const float* __restrict__ ratio_p,
    const float* __restrict__ att_p,
    const float* __restrict__ rel_p,
    float* __restrict__ out)
{
    __shared__ float buf[TILE]; // 16 KiB -> 8 blocks/CU (wave-capped)

    const int tid  = threadIdx.x;
    const int lane = tid & 63;
    const int wv   = tid >> 6;                       // wave id in block
    const long long tile0 = (long long)blockIdx.x * TILE;
    const long long wreg0 = tile0 + (long long)wv * WREG;
    float* wbuf = buf + wv * WREG;                   // this wave's region

    const float thr   = *thr_p;
    const float ratio = *ratio_p;
    const float att   = *att_p;
    const float rel   = *rel_p;
    const float sfac  = 1.0f - 1.0f / ratio;
    const float GA    = thr * sfac;                     // grd = max(GB2*log2(y)+GA, 0)
    const float GB2   = -20.0f * sfac * 0.30102999566f; // log10(y)=log2(y)*log10(2)
    const float KEXP  = -0.05f * 3.32192809489f;        // 10^(-g/20) = 2^(KEXP*g)
    const float omc_att = 1.0f - att;
    const float omc_rel = 1.0f - rel;

    // Only (block 0, wave 0, lane 0) has no history at all.
    const bool has_warm = (blockIdx.x > 0) || (wv > 0) || (lane > 0);

    // Lane 0 of each wave: 12-sample history from global (prev wave region /
    // prev tile). wreg0 - 12 is 16B-aligned (wreg0 % 1024 == 0). Issued
    // before phase 1 so the latency hides under the region load.
    float4 wg0 = {0,0,0,0}, wg1 = {0,0,0,0}, wg2 = {0,0,0,0};
    if (lane == 0 && (blockIdx.x > 0 || wv > 0)) {
        const float4* wp = reinterpret_cast<const float4*>(audio + wreg0 - W);
        wg0 = wp[0]; wg1 = wp[1]; wg2 = wp[2]; // 48 B
    }

    // ---- Phase 1: wave-local coalesced float4 global -> swizzled LDS ----
    // Lane l, iter k loads region elements k*256 + l*4 .. +3 (1 KB/instr).
    const float4* a4 = reinterpret_cast<const float4*>(audio + wreg0);
#pragma unroll
    for (int k = 0; k < 4; ++k) {
        const float4 v = a4[k * 64 + lane];
        const int li   = k * 256 + lane * 4;
        const int base = li & ~31;
        const int j0   = li & 31;          // 4-aligned, j0+3 <= 31
        const int key  = (li >> 5) & 31;
        wbuf[base + ((j0 + 0) ^ key)] = v.x;
        wbuf[base + ((j0 + 1) ^ key)] = v.y;
        wbuf[base + ((j0 + 2) ^ key)] = v.z;
        wbuf[base + ((j0 + 3) ^ key)] = v.w;
    }
    // Same-wave producer->consumer: drain DS (and block compiler reordering).
    asm volatile("s_waitcnt lgkmcnt(0)" ::: "memory");

    // ---- Warm-up samples: lane l>0 reads lane l-1's chunk tail (same wave)
    float xw[W];
    if (lane > 0) {
        const int p0 = lane * C - W;
#pragma unroll
        for (int i = 0; i < W; ++i)
            xw[i] = wbuf[sw(p0 + i)];
    } else {
        xw[0]=wg0.x; xw[1]=wg0.y; xw[2] =wg0.z; xw[3] =wg0.w;
        xw[4]=wg1.x; xw[5]=wg1.y; xw[6] =wg1.z; xw[7] =wg1.w;
        xw[8]=wg2.x; xw[9]=wg2.y; xw[10]=wg2.z; xw[11]=wg2.w;
    }

    // ---- Stage A: all grd values (independent -> trans pipe pipelines) ----
    float grdw[W], grdm[C];
#pragma unroll
    for (int i = 0; i < W; ++i) {
        const float y = fabsf(xw[i]) + 1e-5f;
        grdw[i] = fmaxf(fmaf(GB2, __log2f(y), GA), 0.0f);
    }
    const int myb = lane * C;
#pragma unroll
    for (int j = 0; j < C; ++j) {
        const float y = fabsf(wbuf[sw(myb + j)]) + 1e-5f;
        grdm[j] = fmaxf(fmaf(GB2, __log2f(y), GA), 0.0f);
    }

    // ---- Stage B: tight recurrence, chain = {fma || fma} -> max ----
    // Exact vs the reference branch: ga-gr = (rel-att)*(grd-g), rel>att
    // -> max picks the attack form iff grd > g.
    float g = 0.0f;
    if (has_warm) {
#pragma unroll
        for (int i = 0; i < W; ++i) {
            const float ga = fmaf(att, g, omc_att * grdw[i]);
            const float gr = fmaf(rel, g, omc_rel * grdw[i]);
            g = fmaxf(ga, gr);
        }
    }
#pragma unroll
    for (int j = 0; j < C; ++j) {
        const float ga = fmaf(att, g, omc_att * grdm[j]);
        const float gr = fmaf(rel, g, omc_rel * grdm[j]);
        g = fmaxf(ga, gr);
        grdm[j] = g; // reuse register array for the smoothed gain
    }

    // ---- Stage C: out = x * 2^(KEXP*g), in place (own chunk only).
    // Safe without barrier: the neighbor's warm-up reads of this chunk are
    // earlier instructions of the SAME wave (lockstep, in-order DS pipe),
    // and these writes are data-dependent on those reads (xw->g->product),
    // so neither compiler nor HW can reorder them ahead.
#pragma unroll
    for (int j = 0; j < C; ++j) {
        const int s = sw(myb + j);
        wbuf[s] = wbuf[s] * __builtin_amdgcn_exp2f(KEXP * grdm[j]);
    }
    asm volatile("s_waitcnt lgkmcnt(0)" ::: "memory");

    // ---- Phase 3: swizzled LDS -> wave-local coalesced float4 global ----
    float4* o4 = reinterpret_cast<float4*>(out + wreg0);
#pragma unroll
    for (int k = 0; k < 4; ++k) {
        const int li   = k * 256 + lane * 4;
        const int base = li & ~31;
        const int j0   = li & 31;
        const int key  = (li >> 5) & 31;
        float4 v;
        v.x = wbuf[base + ((j0 + 0) ^ key)];
        v.y = wbuf[base + ((j0 + 1) ^ key)];
        v.z = wbuf[base + ((j0 + 2) ^ key)];
        v.w = wbuf[base + ((j0 + 3) ^ key)];
        o4[k * 64 + lane] = v;
    }
}

extern "C" void kernel_launch(void* const* d_in, const int* in_sizes, int n_in,
                              void* d_out, int out_size, void* d_ws, size_t ws_size,
                              hipStream_t stream) {
    const float* audio = (const float*)d_in[0];
    // d_in[1] = sample_rate (int) — unused by the reference math
    const float* thr   = (const float*)d_in[2];
    const float* ratio = (const float*)d_in[3];
    const float* att   = (const float*)d_in[4];
    const float* rel   = (const float*)d_in[5];
    float* outp = (float*)d_out;

    const int n = in_sizes[0];   // 1<<25 elements, divisible by TILE (4096)
    const int grid = n / TILE;   // 8192 blocks
    compressor_kernel<<<grid, T, 0, stream>>>(audio, thr, ratio, att, rel, outp);
}